// Round 6
// baseline (597.606 us; speedup 1.0000x reference)
//
#include <hip/hip_runtime.h>

#define INF_F __builtin_inff()

typedef unsigned short u16;
typedef __attribute__((ext_vector_type(8))) short s16x8;   // 8 bf16 (4 VGPRs)
typedef __attribute__((ext_vector_type(4))) float f32x4;   // MFMA accum

union U8 { uint4 q; s16x8 v; };

__device__ __forceinline__ float b2f(u16 u) {
    union { unsigned int i; float f; } v; v.i = ((unsigned int)u) << 16; return v.f;
}
__device__ __forceinline__ u16 f2b(float f) {
    union { float f; unsigned int i; } v; v.f = f;
    unsigned int r = (v.i + 0x7FFFu + ((v.i >> 16) & 1u)) >> 16;
    return (u16)r;
}
__device__ __forceinline__ void bf2x(unsigned int p, float& lo, float& hi) {
    union { unsigned int i; float f; } a, b;
    a.i = p << 16; b.i = p & 0xFFFF0000u;
    lo = a.f; hi = b.f;
}
__device__ __forceinline__ unsigned int packbf(float lo, float hi) {
    return (unsigned int)f2b(lo) | ((unsigned int)f2b(hi) << 16);
}

// ---------------------------------------------------------------------------
// Pack a fp32 weight [K][N] into bf16 MFMA-B-fragment layout, N padded to Npad
// (pad cols = 0). A wave reads frag (colblock cb, kblock k5) as contiguous
// 1KB at pb + (cb*(K/32)+k5)*512 + lane*8.
// ---------------------------------------------------------------------------
__launch_bounds__(256)
__global__ void k_packB(const float* __restrict__ W, int K, int N, int Npad,
                        u16* __restrict__ pb)
{
    int idx = blockIdx.x * 256 + threadIdx.x;
    if (idx >= K * Npad) return;
    int k = idx / Npad, n = idx - k * Npad;
    float v = (n < N) ? W[(size_t)k * N + n] : 0.f;
    int K5 = K >> 5;
    size_t o = ((size_t)(n >> 4) * K5 + (k >> 5)) * 512
             + ((size_t)((k >> 3) & 3)) * 128 + (n & 15) * 8 + (k & 7);
    pb[o] = f2b(v);
}

// ---------------------------------------------------------------------------
// MFMA GEMM: C(bf16) = act(A' @ B [+bias]); A'[r,k]=A[r,k]*scale[k]+shift[k].
// No LDS / no barriers: wave w owns rows [row0+16w,+16); B frags read from
// packed pb (L2-resident); A frag = one 16B(bf16)/32B(fp32) load per lane.
// HEADS_PB>0: fused GAT alpha epilogue (head width = 128 cols, deterministic).
// ---------------------------------------------------------------------------
template<int NFRAG, bool A_FP32, bool BN_A, bool BIAS, bool LRELU, int HEADS_PB>
__launch_bounds__(256)
__global__ void k_mgemm(const void* __restrict__ Av, int lda, int K,
                        const u16* __restrict__ pb,
                        u16* __restrict__ C, int ldc, int M,
                        const float* __restrict__ scale, const float* __restrict__ shift,
                        const float* __restrict__ bias,
                        const float* __restrict__ aw_s, const float* __restrict__ aw_d,
                        float* __restrict__ as_o, float* __restrict__ ad_o, int nheads)
{
    const int tid = threadIdx.x;
    const int w = tid >> 6, l = tid & 63;
    const int lo = l & 15, hi = l >> 4;
    const int row0 = blockIdx.y * 64 + w * 16;
    if (row0 >= M) return;
    const int cb0 = blockIdx.x * NFRAG;
    const int K5 = K >> 5;

    f32x4 acc[NFRAG];
    #pragma unroll
    for (int i = 0; i < NFRAG; ++i) acc[i] = (f32x4){0.f, 0.f, 0.f, 0.f};

    int arow = row0 + lo; if (arow >= M) arow = M - 1;

    for (int k5 = 0; k5 < K5; ++k5) {
        const int ak = k5 * 32 + hi * 8;
        float x[8];
        if (A_FP32) {
            const float* A = (const float*)Av + (size_t)arow * lda + ak;
            float4 v0 = *reinterpret_cast<const float4*>(A);
            float4 v1 = *reinterpret_cast<const float4*>(A + 4);
            x[0]=v0.x; x[1]=v0.y; x[2]=v0.z; x[3]=v0.w;
            x[4]=v1.x; x[5]=v1.y; x[6]=v1.z; x[7]=v1.w;
        } else {
            uint4 q = *reinterpret_cast<const uint4*>((const u16*)Av + (size_t)arow * lda + ak);
            bf2x(q.x, x[0], x[1]); bf2x(q.y, x[2], x[3]);
            bf2x(q.z, x[4], x[5]); bf2x(q.w, x[6], x[7]);
        }
        if (BN_A) {
            #pragma unroll
            for (int j = 0; j < 8; ++j) x[j] = fmaf(x[j], scale[ak + j], shift[ak + j]);
        }
        U8 au;
        au.q.x = packbf(x[0], x[1]); au.q.y = packbf(x[2], x[3]);
        au.q.z = packbf(x[4], x[5]); au.q.w = packbf(x[6], x[7]);
        s16x8 af = au.v;
        #pragma unroll
        for (int cb = 0; cb < NFRAG; ++cb) {
            s16x8 bf = *reinterpret_cast<const s16x8*>(
                pb + ((size_t)(cb0 + cb) * K5 + k5) * 512 + l * 8);
            acc[cb] = __builtin_amdgcn_mfma_f32_16x16x32_bf16(af, bf, acc[cb], 0, 0, 0);
        }
    }

    // C store: D lane layout col=lo, row=hi*4+p
    #pragma unroll
    for (int cb = 0; cb < NFRAG; ++cb) {
        int col = (cb0 + cb) * 16 + lo;
        #pragma unroll
        for (int p = 0; p < 4; ++p) {
            int r = row0 + hi * 4 + p;
            if (r < M) {
                float v = acc[cb][p];
                if (BIAS)  v += bias[col];
                if (LRELU) v = v >= 0.f ? v : 0.01f * v;
                C[(size_t)r * ldc + col] = f2b(v);
            }
        }
    }

    if (HEADS_PB > 0) {
        const int CBH = NFRAG / HEADS_PB;   // 8 col-frags per head (head width 128)
        #pragma unroll
        for (int hl = 0; hl < HEADS_PB; ++hl) {
            float ps[4] = {0.f,0.f,0.f,0.f}, pd[4] = {0.f,0.f,0.f,0.f};
            #pragma unroll
            for (int cc = 0; cc < CBH; ++cc) {
                int cb = hl * CBH + cc;
                int col = (cb0 + cb) * 16 + lo;
                float ws = aw_s[col], wd = aw_d[col];
                #pragma unroll
                for (int p = 0; p < 4; ++p) {
                    ps[p] = fmaf(acc[cb][p], ws, ps[p]);
                    pd[p] = fmaf(acc[cb][p], wd, pd[p]);
                }
            }
            #pragma unroll
            for (int m = 1; m < 16; m <<= 1) {
                #pragma unroll
                for (int p = 0; p < 4; ++p) {
                    ps[p] += __shfl_xor(ps[p], m, 64);
                    pd[p] += __shfl_xor(pd[p], m, 64);
                }
            }
            if (lo == 0) {
                int h = (cb0 >> 3) + hl;
                #pragma unroll
                for (int p = 0; p < 4; ++p) {
                    int r = row0 + hi * 4 + p;
                    if (r < M) {
                        as_o[(size_t)r * nheads + h] = ps[p];
                        ad_o[(size_t)r * nheads + h] = pd[p];
                    }
                }
            }
        }
    }
}

// ---------------------------------------------------------------------------
// Final MFMA GEMM over concat [bn1(h1)|bn2(h2)|bn3(h3)] (K=768) with packed
// l2_W (40 cols zero-padded to 64), fused bias + log_softmax. out fp32 [M,40].
// ---------------------------------------------------------------------------
__launch_bounds__(256)
__global__ void k_mfinal(const u16* __restrict__ h1, const u16* __restrict__ h2,
                         const u16* __restrict__ h3,
                         const float* __restrict__ scale, const float* __restrict__ shift,
                         const u16* __restrict__ pb, const float* __restrict__ bias,
                         float* __restrict__ out, int M)
{
    const int tid = threadIdx.x;
    const int w = tid >> 6, l = tid & 63;
    const int lo = l & 15, hi = l >> 4;
    const int row0 = blockIdx.x * 64 + w * 16;
    if (row0 >= M) return;
    const int K5 = 24;   // 768/32

    f32x4 acc[4];
    #pragma unroll
    for (int i = 0; i < 4; ++i) acc[i] = (f32x4){0.f, 0.f, 0.f, 0.f};

    int arow = row0 + lo; if (arow >= M) arow = M - 1;

    for (int k5 = 0; k5 < K5; ++k5) {
        const int kk = k5 * 32 + hi * 8;   // region-uniform per k5 (32-aligned splits)
        const u16* src; int ld, offk;
        if (kk < 128)      { src = h1; ld = 128; offk = kk; }
        else if (kk < 640) { src = h2; ld = 512; offk = kk - 128; }
        else               { src = h3; ld = 128; offk = kk - 640; }
        uint4 q = *reinterpret_cast<const uint4*>(src + (size_t)arow * ld + offk);
        float x[8];
        bf2x(q.x, x[0], x[1]); bf2x(q.y, x[2], x[3]);
        bf2x(q.z, x[4], x[5]); bf2x(q.w, x[6], x[7]);
        #pragma unroll
        for (int j = 0; j < 8; ++j) x[j] = fmaf(x[j], scale[kk + j], shift[kk + j]);
        U8 au;
        au.q.x = packbf(x[0], x[1]); au.q.y = packbf(x[2], x[3]);
        au.q.z = packbf(x[4], x[5]); au.q.w = packbf(x[6], x[7]);
        s16x8 af = au.v;
        #pragma unroll
        for (int cb = 0; cb < 4; ++cb) {
            s16x8 bf = *reinterpret_cast<const s16x8*>(pb + ((size_t)cb * K5 + k5) * 512 + l * 8);
            acc[cb] = __builtin_amdgcn_mfma_f32_16x16x32_bf16(af, bf, acc[cb], 0, 0, 0);
        }
    }

    // bias + log_softmax over 40 valid cols (cb2 valid iff lo<8; cb3 all pad)
    #pragma unroll
    for (int p = 0; p < 4; ++p) {
        int r = row0 + hi * 4 + p;
        float z0 = acc[0][p] + bias[lo];
        float z1 = acc[1][p] + bias[16 + lo];
        float z2 = -INF_F;
        if (lo < 8) z2 = acc[2][p] + bias[32 + lo];
        float mx = fmaxf(fmaxf(z0, z1), z2);
        #pragma unroll
        for (int m = 1; m < 16; m <<= 1) mx = fmaxf(mx, __shfl_xor(mx, m, 64));
        float se = __expf(z0 - mx) + __expf(z1 - mx) + ((lo < 8) ? __expf(z2 - mx) : 0.f);
        #pragma unroll
        for (int m = 1; m < 16; m <<= 1) se += __shfl_xor(se, m, 64);
        float lse = mx + __logf(se);
        if (r < M) {
            out[(size_t)r * 40 + lo]      = z0 - lse;
            out[(size_t)r * 40 + 16 + lo] = z1 - lse;
            if (lo < 8) out[(size_t)r * 40 + 32 + lo] = z2 - lse;
        }
    }
}

// ---------------------------------------------------------------------------
// BN stats stage 1: per-block column partial sums/sumsq of bf16 matrix.
// ---------------------------------------------------------------------------
__launch_bounds__(256)
__global__ void k_colstats(const u16* __restrict__ X, int M, int C,
                           float* __restrict__ psum, float* __restrict__ psq)
{
    const int CG  = C >> 3;
    const int RPI = 256 / CG;
    const int tid = threadIdx.x;
    const int cg  = tid & (CG - 1);
    const int ro  = tid / CG;
    const int nb  = gridDim.x;
    const int rows_chunk = (M + nb - 1) / nb;
    const int r0 = blockIdx.x * rows_chunk;
    const int r1 = min(M, r0 + rows_chunk);

    float s[8] = {}, q[8] = {};
    for (int r = r0 + ro; r < r1; r += RPI) {
        uint4 u = *reinterpret_cast<const uint4*>(X + (size_t)r * C + cg * 8);
        float x[8];
        bf2x(u.x, x[0], x[1]); bf2x(u.y, x[2], x[3]);
        bf2x(u.z, x[4], x[5]); bf2x(u.w, x[6], x[7]);
        #pragma unroll
        for (int j = 0; j < 8; ++j) { s[j] += x[j]; q[j] = fmaf(x[j], x[j], q[j]); }
    }

    __shared__ float lsum[8][256];
    __shared__ float lsq [8][256];
    #pragma unroll
    for (int j = 0; j < 8; ++j) { lsum[j][tid] = s[j]; lsq[j][tid] = q[j]; }
    __syncthreads();

    if (tid < CG) {
        #pragma unroll
        for (int j = 0; j < 8; ++j) {
            float ss = 0.f, qq = 0.f;
            for (int o = 0; o < RPI; ++o) {
                ss += lsum[j][o * CG + tid];
                qq += lsq [j][o * CG + tid];
            }
            psum[(size_t)blockIdx.x * C + tid * 8 + j] = ss;
            psq [(size_t)blockIdx.x * C + tid * 8 + j] = qq;
        }
    }
}

__launch_bounds__(256)
__global__ void k_colred(const float* __restrict__ psum, const float* __restrict__ psq,
                         const float* __restrict__ g, const float* __restrict__ b,
                         int nb, int M, int C,
                         float* __restrict__ scale, float* __restrict__ shift)
{
    int c = blockIdx.x * 4 + (threadIdx.x >> 6);
    int lane = threadIdx.x & 63;
    if (c >= C) return;
    float s = 0.f, q = 0.f;
    for (int l = lane; l < nb; l += 64) {
        s += psum[(size_t)l * C + c];
        q += psq [(size_t)l * C + c];
    }
    #pragma unroll
    for (int off = 32; off; off >>= 1) {
        s += __shfl_xor(s, off, 64);
        q += __shfl_xor(q, off, 64);
    }
    if (lane == 0) {
        float mu  = s / (float)M;
        float var = q / (float)M - mu * mu;
        float sc  = g[c] * rsqrtf(var + 1e-5f);
        scale[c] = sc;
        shift[c] = b[c] - mu * sc;
    }
}

// ---------------------------------------------------------------------------
// CSR build: count -> scan -> scatter
// ---------------------------------------------------------------------------
__launch_bounds__(256)
__global__ void k_count(const int* __restrict__ dst, int E, int* __restrict__ counts)
{
    int e = blockIdx.x * 256 + threadIdx.x;
    if (e < E) atomicAdd(&counts[dst[e]], 1);
}

__launch_bounds__(1024)
__global__ void k_scan(const int* __restrict__ counts, int* __restrict__ rowstart, int n)
{
    __shared__ int wsum[16];
    __shared__ int s_carry;
    int tid = threadIdx.x, lane = tid & 63, w = tid >> 6;
    if (tid == 0) { s_carry = 0; rowstart[0] = 0; }
    __syncthreads();
    for (int base = 0; base < n; base += 1024) {
        int carry = s_carry;
        int v = (base + tid < n) ? counts[base + tid] : 0;
        int x = v;
        #pragma unroll
        for (int off = 1; off < 64; off <<= 1) {
            int t = __shfl_up(x, off, 64);
            if (lane >= off) x += t;
        }
        if (lane == 63) wsum[w] = x;
        __syncthreads();
        int woff = 0;
        #pragma unroll
        for (int i = 0; i < 16; ++i)
            if (i < w) woff += wsum[i];
        int incl = carry + woff + x;
        if (base + tid < n) rowstart[base + tid + 1] = incl;
        __syncthreads();
        if (tid == 1023) s_carry = incl;
        __syncthreads();
    }
}

__launch_bounds__(256)
__global__ void k_scatter(const int* __restrict__ ei, int E,
                          const int* __restrict__ rowstart,
                          int* __restrict__ fill, int* __restrict__ csr)
{
    int e = blockIdx.x * 256 + threadIdx.x;
    if (e >= E) return;
    int s = ei[e], d = ei[E + e];
    int pos = rowstart[d] + atomicAdd(&fill[d], 1);
    csr[pos] = s;
}

// ---------------------------------------------------------------------------
// GAT aggregation, HEADS=4, TWO-PASS softmax. One wave per dst covers all
// heads. Pass 1: per-head max, lane-parallel (16 lanes stride the edge list,
// scalar as_ reads only) + shfl reduce. Pass 2: depth-2 prefetch gather with
// NO rescale: w=exp(e-mx) final, acc[t]=fmaf(x[t],w,acc[t]) independent FMAs.
// ---------------------------------------------------------------------------
__launch_bounds__(256)
__global__ void k_gat_agg_h4(const u16* __restrict__ hp,
                             const float* __restrict__ as_, const float* __restrict__ ad_,
                             const int* __restrict__ rowstart, const int* __restrict__ csr,
                             const float* __restrict__ bias, u16* __restrict__ out, int Nn)
{
    int d = (int)((blockIdx.x * (size_t)blockDim.x + threadIdx.x) >> 6);
    int lane = threadIdx.x & 63;
    if (d >= Nn) return;
    const int h = lane >> 4;
    const int li = lane & 15;
    const int dim = li * 8;
    int e0 = rowstart[d], e1 = rowstart[d + 1];
    float adv = ad_[(size_t)d * 4 + h];

    // ---- pass 1: per-head max (lane-parallel over edges) ----
    float mx = -INF_F;
    for (int j = e0 + li; j < e1; j += 16) {
        int s = csr[j];
        float e = as_[(size_t)s * 4 + h] + adv;
        e = e >= 0.f ? e : 0.2f * e;
        mx = fmaxf(mx, e);
    }
    #pragma unroll
    for (int m = 1; m < 16; m <<= 1) mx = fmaxf(mx, __shfl_xor(mx, m, 64));

    // ---- pass 2: weighted accumulate, depth-2 pipeline, no rescale ----
    float lsum = 0.f;
    float acc[8] = {};

    int s0 = csr[e0];
    float a0 = as_[(size_t)s0 * 4 + h];
    uint4 u0 = *reinterpret_cast<const uint4*>(hp + ((size_t)s0 * 4 + h) * 128 + dim);
    float a1 = 0.f; uint4 u1 = u0;
    if (e0 + 1 < e1) {
        int s1 = csr[e0 + 1];
        a1 = as_[(size_t)s1 * 4 + h];
        u1 = *reinterpret_cast<const uint4*>(hp + ((size_t)s1 * 4 + h) * 128 + dim);
    }

    for (int j = e0; j < e1; ++j) {
        float e = a0 + adv;
        uint4 u = u0;
        a0 = a1; u0 = u1;
        if (j + 2 < e1) {
            int sn = csr[j + 2];
            a1 = as_[(size_t)sn * 4 + h];
            u1 = *reinterpret_cast<const uint4*>(hp + ((size_t)sn * 4 + h) * 128 + dim);
        }
        e = e >= 0.f ? e : 0.2f * e;
        float w = __expf(e - mx);
        lsum += w;
        float x[8];
        bf2x(u.x, x[0], x[1]); bf2x(u.y, x[2], x[3]);
        bf2x(u.z, x[4], x[5]); bf2x(u.w, x[6], x[7]);
        #pragma unroll
        for (int t = 0; t < 8; ++t) acc[t] = fmaf(x[t], w, acc[t]);
    }

    float inv = 1.f / (lsum + 1e-16f);
    const int ob = h * 128 + dim;
    float v[8];
    #pragma unroll
    for (int t = 0; t < 8; ++t) {
        float z = acc[t] * inv + bias[ob + t];
        v[t] = z >= 0.f ? z : 0.01f * z;
    }
    uint4 o;
    o.x = packbf(v[0], v[1]); o.y = packbf(v[2], v[3]);
    o.z = packbf(v[4], v[5]); o.w = packbf(v[6], v[7]);
    *reinterpret_cast<uint4*>(out + (size_t)d * 512 + ob) = o;
}

// ---------------------------------------------------------------------------
// GAT aggregation, HEADS=1, TWO-PASS softmax (same structure).
// ---------------------------------------------------------------------------
__launch_bounds__(256)
__global__ void k_gat_agg_h1(const u16* __restrict__ hp,
                             const float* __restrict__ as_, const float* __restrict__ ad_,
                             const int* __restrict__ rowstart, const int* __restrict__ csr,
                             const float* __restrict__ bias, u16* __restrict__ out, int Nn)
{
    int d = (int)((blockIdx.x * (size_t)blockDim.x + threadIdx.x) >> 6);
    int lane = threadIdx.x & 63;
    if (d >= Nn) return;
    const int dim = lane * 2;
    int e0 = rowstart[d], e1 = rowstart[d + 1];
    float adv = ad_[d];

    // ---- pass 1: max, all 64 lanes stride edges ----
    float mx = -INF_F;
    for (int j = e0 + lane; j < e1; j += 64) {
        int s = csr[j];
        float e = as_[s] + adv;
        e = e >= 0.f ? e : 0.2f * e;
        mx = fmaxf(mx, e);
    }
    #pragma unroll
    for (int m = 1; m < 64; m <<= 1) mx = fmaxf(mx, __shfl_xor(mx, m, 64));

    // ---- pass 2 ----
    float lsum = 0.f, acc0 = 0.f, acc1 = 0.f;

    int s0 = csr[e0];
    float a0 = as_[s0];
    unsigned int u0 = *reinterpret_cast<const unsigned int*>(hp + (size_t)s0 * 128 + dim);
    float a1 = 0.f; unsigned int u1 = u0;
    if (e0 + 1 < e1) {
        int s1 = csr[e0 + 1];
        a1 = as_[s1];
        u1 = *reinterpret_cast<const unsigned int*>(hp + (size_t)s1 * 128 + dim);
    }

    for (int j = e0; j < e1; ++j) {
        float e = a0 + adv;
        unsigned int u = u0;
        a0 = a1; u0 = u1;
        if (j + 2 < e1) {
            int sn = csr[j + 2];
            a1 = as_[sn];
            u1 = *reinterpret_cast<const unsigned int*>(hp + (size_t)sn * 128 + dim);
        }
        e = e >= 0.f ? e : 0.2f * e;
        float w = __expf(e - mx);
        float x0, x1;
        bf2x(u, x0, x1);
        lsum += w;
        acc0 = fmaf(x0, w, acc0);
        acc1 = fmaf(x1, w, acc1);
    }

    float inv = 1.f / (lsum + 1e-16f);
    float v0 = acc0 * inv + bias[dim];
    float v1 = acc1 * inv + bias[dim + 1];
    v0 = v0 >= 0.f ? v0 : 0.01f * v0;
    v1 = v1 >= 0.f ? v1 : 0.01f * v1;
    *reinterpret_cast<unsigned int*>(out + (size_t)d * 128 + dim) = packbf(v0, v1);
}

// ---------------------------------------------------------------------------
extern "C" void kernel_launch(void* const* d_in, const int* in_sizes, int n_in,
                              void* d_out, int out_size, void* d_ws, size_t ws_size,
                              hipStream_t stream)
{
    const float* x     = (const float*)d_in[0];
    const int*   ei    = (const int*)  d_in[1];
    const float* fw_W  = (const float*)d_in[2];
    const float* fw_b  = (const float*)d_in[3];
    const float* c1_W  = (const float*)d_in[4];
    const float* c1_as = (const float*)d_in[5];
    const float* c1_ad = (const float*)d_in[6];
    const float* c1_b  = (const float*)d_in[7];
    const float* c2_W  = (const float*)d_in[8];
    const float* c2_as = (const float*)d_in[9];
    const float* c2_ad = (const float*)d_in[10];
    const float* c2_b  = (const float*)d_in[11];
    const float* bn1_g = (const float*)d_in[12];
    const float* bn1_b = (const float*)d_in[13];
    const float* bn2_g = (const float*)d_in[14];
    const float* bn2_b = (const float*)d_in[15];
    const float* bn3_g = (const float*)d_in[16];
    const float* bn3_b = (const float*)d_in[17];
    const float* l2_W  = (const float*)d_in[18];
    const float* l2_b  = (const float*)d_in[19];
    float* out = (float*)d_out;

    const int N = in_sizes[0] / 256;   // 50000
    const int E = in_sizes[1] / 2;     // 850000
    const int NB = 256;

    char* base = (char*)d_ws;
    size_t off = 0;
    auto alloc = [&](size_t bytes) -> void* {
        void* p = (void*)(base + off);
        off = (off + bytes + 255) & ~(size_t)255;
        return p;
    };
    // --- zeroed region (counts, fill) ---
    int*   counts = (int*)  alloc((size_t)N * 4);
    int*   fill   = (int*)  alloc((size_t)N * 4);
    size_t zero_bytes = off;
    // --- rest ---
    float* as1      = (float*)alloc((size_t)N * 4 * 4);
    float* ad1      = (float*)alloc((size_t)N * 4 * 4);
    float* as2      = (float*)alloc((size_t)N * 4);
    float* ad2      = (float*)alloc((size_t)N * 4);
    float* psum     = (float*)alloc((size_t)NB * 512 * 4);
    float* psq      = (float*)alloc((size_t)NB * 512 * 4);
    int*   rowstart = (int*)  alloc((size_t)(N + 1) * 4);
    int*   csr      = (int*)  alloc((size_t)E * 4);
    float* scale768 = (float*)alloc(768 * 4);
    float* shift768 = (float*)alloc(768 * 4);
    u16*   pb_l1    = (u16*)  alloc((size_t)256 * 128 * 2);
    u16*   pb_c1    = (u16*)  alloc((size_t)128 * 512 * 2);
    u16*   pb_c2    = (u16*)  alloc((size_t)512 * 128 * 2);
    u16*   pb_f     = (u16*)  alloc((size_t)768 * 64 * 2);
    u16*   h1       = (u16*)  alloc((size_t)N * 128 * 2);
    u16*   h2       = (u16*)  alloc((size_t)N * 512 * 2);
    u16*   hp1      = (u16*)  alloc((size_t)N * 512 * 2);  // dead after agg1:
    u16*   hp2      = hp1;                                  //  reuse for hp2 [N,128]
    u16*   h3       = hp1 + (size_t)N * 128;                //  and h3 [N,128]
    (void)ws_size; (void)n_in; (void)out_size;

    const int mb = (N + 63) / 64;
    const int wave_blocks = (int)(((size_t)N * 64 + 255) / 256);

    hipMemsetAsync(base, 0, zero_bytes, stream);

    // pack weights into MFMA-B layout (tiny)
    k_packB<<<(256 * 128 + 255) / 256, 256, 0, stream>>>(fw_W, 256, 128, 128, pb_l1);
    k_packB<<<(128 * 512 + 255) / 256, 256, 0, stream>>>(c1_W, 128, 512, 512, pb_c1);
    k_packB<<<(512 * 128 + 255) / 256, 256, 0, stream>>>(c2_W, 512, 128, 128, pb_c2);
    k_packB<<<(768 *  64 + 255) / 256, 256, 0, stream>>>(l2_W, 768,  40,  64, pb_f);

    // CSR build (independent)
    k_count<<<(E + 255) / 256, 256, 0, stream>>>(ei + E, E, counts);
    k_scan<<<1, 1024, 0, stream>>>(counts, rowstart, N);
    k_scatter<<<(E + 255) / 256, 256, 0, stream>>>(ei, E, rowstart, fill, csr);

    // layer 1: h1 = lrelu(x @ fw_W + fw_b)
    k_mgemm<8, true, false, true, true, 0><<<dim3(1, mb), 256, 0, stream>>>(
        x, 256, 256, pb_l1, h1, 128, N, nullptr, nullptr, fw_b,
        nullptr, nullptr, nullptr, nullptr, 0);

    // BN1
    k_colstats<<<NB, 256, 0, stream>>>(h1, N, 128, psum, psq);
    k_colred<<<(128 + 3) / 4, 256, 0, stream>>>(psum, psq, bn1_g, bn1_b, NB, N, 128,
                                                scale768, shift768);

    // conv1 projection: hp1 = bn1(h1) @ c1_W [N,512] + fused alpha (2 heads/block)
    k_mgemm<16, false, true, false, false, 2><<<dim3(2, mb), 256, 0, stream>>>(
        h1, 128, 128, pb_c1, hp1, 512, N, scale768, shift768, nullptr,
        c1_as, c1_ad, as1, ad1, 4);
    k_gat_agg_h4<<<wave_blocks, 256, 0, stream>>>(
        hp1, as1, ad1, rowstart, csr, c1_b, h2, N);

    // BN2
    k_colstats<<<NB, 256, 0, stream>>>(h2, N, 512, psum, psq);
    k_colred<<<(512 + 3) / 4, 256, 0, stream>>>(psum, psq, bn2_g, bn2_b, NB, N, 512,
                                                scale768 + 128, shift768 + 128);

    // conv2 projection: hp2 = bn2(h2) @ c2_W [N,128] + fused alpha (1 head)
    k_mgemm<8, false, true, false, false, 1><<<dim3(1, mb), 256, 0, stream>>>(
        h2, 512, 512, pb_c2, hp2, 128, N, scale768 + 128, shift768 + 128, nullptr,
        c2_as, c2_ad, as2, ad2, 1);
    k_gat_agg_h1<<<wave_blocks, 256, 0, stream>>>(
        hp2, as2, ad2, rowstart, csr, c2_b, h3, N);

    // BN3
    k_colstats<<<NB, 256, 0, stream>>>(h3, N, 128, psum, psq);
    k_colred<<<(128 + 3) / 4, 256, 0, stream>>>(psum, psq, bn3_g, bn3_b, NB, N, 128,
                                                scale768 + 640, shift768 + 640);

    // final fused GEMM + log_softmax
    k_mfinal<<<mb, 256, 0, stream>>>(h1, h2, h3, scale768, shift768, pb_f, l2_b, out, N);
}

// Round 7
// 558.579 us; speedup vs baseline: 1.0699x; 1.0699x over previous
//
#include <hip/hip_runtime.h>

#define INF_F __builtin_inff()

typedef unsigned short u16;
typedef __attribute__((ext_vector_type(8))) short s16x8;   // 8 bf16 (4 VGPRs)
typedef __attribute__((ext_vector_type(4))) float f32x4;   // MFMA accum

union U8 { uint4 q; s16x8 v; };

__device__ __forceinline__ float b2f(u16 u) {
    union { unsigned int i; float f; } v; v.i = ((unsigned int)u) << 16; return v.f;
}
__device__ __forceinline__ u16 f2b(float f) {
    union { float f; unsigned int i; } v; v.f = f;
    unsigned int r = (v.i + 0x7FFFu + ((v.i >> 16) & 1u)) >> 16;
    return (u16)r;
}
__device__ __forceinline__ void bf2x(unsigned int p, float& lo, float& hi) {
    union { unsigned int i; float f; } a, b;
    a.i = p << 16; b.i = p & 0xFFFF0000u;
    lo = a.f; hi = b.f;
}
__device__ __forceinline__ unsigned int packbf(float lo, float hi) {
    return (unsigned int)f2b(lo) | ((unsigned int)f2b(hi) << 16);
}

// ---------------------------------------------------------------------------
// Pack a fp32 weight [K][N] into bf16 MFMA-B-fragment layout, N padded to Npad
// (pad cols = 0). A wave reads frag (colblock cb, kblock k5) as contiguous
// 1KB at pb + (cb*(K/32)+k5)*512 + lane*8.
// ---------------------------------------------------------------------------
__launch_bounds__(256)
__global__ void k_packB(const float* __restrict__ W, int K, int N, int Npad,
                        u16* __restrict__ pb)
{
    int idx = blockIdx.x * 256 + threadIdx.x;
    if (idx >= K * Npad) return;
    int k = idx / Npad, n = idx - k * Npad;
    float v = (n < N) ? W[(size_t)k * N + n] : 0.f;
    int K5 = K >> 5;
    size_t o = ((size_t)(n >> 4) * K5 + (k >> 5)) * 512
             + ((size_t)((k >> 3) & 3)) * 128 + (n & 15) * 8 + (k & 7);
    pb[o] = f2b(v);
}

// ---------------------------------------------------------------------------
// MFMA GEMM: C(bf16) = act(A' @ B [+bias]); A'[r,k]=A[r,k]*scale[k]+shift[k].
// No LDS / no barriers: wave w owns rows [row0+16w,+16); B frags read from
// packed pb (L2-resident); A frag = one 16B(bf16)/32B(fp32) load per lane.
// HEADS_PB>0: fused GAT alpha epilogue (head width = 128 cols, deterministic).
// ---------------------------------------------------------------------------
template<int NFRAG, bool A_FP32, bool BN_A, bool BIAS, bool LRELU, int HEADS_PB>
__launch_bounds__(256)
__global__ void k_mgemm(const void* __restrict__ Av, int lda, int K,
                        const u16* __restrict__ pb,
                        u16* __restrict__ C, int ldc, int M,
                        const float* __restrict__ scale, const float* __restrict__ shift,
                        const float* __restrict__ bias,
                        const float* __restrict__ aw_s, const float* __restrict__ aw_d,
                        float* __restrict__ as_o, float* __restrict__ ad_o, int nheads)
{
    const int tid = threadIdx.x;
    const int w = tid >> 6, l = tid & 63;
    const int lo = l & 15, hi = l >> 4;
    const int row0 = blockIdx.y * 64 + w * 16;
    if (row0 >= M) return;
    const int cb0 = blockIdx.x * NFRAG;
    const int K5 = K >> 5;

    f32x4 acc[NFRAG];
    #pragma unroll
    for (int i = 0; i < NFRAG; ++i) acc[i] = (f32x4){0.f, 0.f, 0.f, 0.f};

    int arow = row0 + lo; if (arow >= M) arow = M - 1;

    for (int k5 = 0; k5 < K5; ++k5) {
        const int ak = k5 * 32 + hi * 8;
        float x[8];
        if (A_FP32) {
            const float* A = (const float*)Av + (size_t)arow * lda + ak;
            float4 v0 = *reinterpret_cast<const float4*>(A);
            float4 v1 = *reinterpret_cast<const float4*>(A + 4);
            x[0]=v0.x; x[1]=v0.y; x[2]=v0.z; x[3]=v0.w;
            x[4]=v1.x; x[5]=v1.y; x[6]=v1.z; x[7]=v1.w;
        } else {
            uint4 q = *reinterpret_cast<const uint4*>((const u16*)Av + (size_t)arow * lda + ak);
            bf2x(q.x, x[0], x[1]); bf2x(q.y, x[2], x[3]);
            bf2x(q.z, x[4], x[5]); bf2x(q.w, x[6], x[7]);
        }
        if (BN_A) {
            #pragma unroll
            for (int j = 0; j < 8; ++j) x[j] = fmaf(x[j], scale[ak + j], shift[ak + j]);
        }
        U8 au;
        au.q.x = packbf(x[0], x[1]); au.q.y = packbf(x[2], x[3]);
        au.q.z = packbf(x[4], x[5]); au.q.w = packbf(x[6], x[7]);
        s16x8 af = au.v;
        #pragma unroll
        for (int cb = 0; cb < NFRAG; ++cb) {
            s16x8 bf = *reinterpret_cast<const s16x8*>(
                pb + ((size_t)(cb0 + cb) * K5 + k5) * 512 + l * 8);
            acc[cb] = __builtin_amdgcn_mfma_f32_16x16x32_bf16(af, bf, acc[cb], 0, 0, 0);
        }
    }

    // C store: D lane layout col=lo, row=hi*4+p
    #pragma unroll
    for (int cb = 0; cb < NFRAG; ++cb) {
        int col = (cb0 + cb) * 16 + lo;
        #pragma unroll
        for (int p = 0; p < 4; ++p) {
            int r = row0 + hi * 4 + p;
            if (r < M) {
                float v = acc[cb][p];
                if (BIAS)  v += bias[col];
                if (LRELU) v = v >= 0.f ? v : 0.01f * v;
                C[(size_t)r * ldc + col] = f2b(v);
            }
        }
    }

    if (HEADS_PB > 0) {
        const int CBH = NFRAG / HEADS_PB;   // 8 col-frags per head (head width 128)
        #pragma unroll
        for (int hl = 0; hl < HEADS_PB; ++hl) {
            float ps[4] = {0.f,0.f,0.f,0.f}, pd[4] = {0.f,0.f,0.f,0.f};
            #pragma unroll
            for (int cc = 0; cc < CBH; ++cc) {
                int cb = hl * CBH + cc;
                int col = (cb0 + cb) * 16 + lo;
                float ws = aw_s[col], wd = aw_d[col];
                #pragma unroll
                for (int p = 0; p < 4; ++p) {
                    ps[p] = fmaf(acc[cb][p], ws, ps[p]);
                    pd[p] = fmaf(acc[cb][p], wd, pd[p]);
                }
            }
            #pragma unroll
            for (int m = 1; m < 16; m <<= 1) {
                #pragma unroll
                for (int p = 0; p < 4; ++p) {
                    ps[p] += __shfl_xor(ps[p], m, 64);
                    pd[p] += __shfl_xor(pd[p], m, 64);
                }
            }
            if (lo == 0) {
                int h = (cb0 >> 3) + hl;
                #pragma unroll
                for (int p = 0; p < 4; ++p) {
                    int r = row0 + hi * 4 + p;
                    if (r < M) {
                        as_o[(size_t)r * nheads + h] = ps[p];
                        ad_o[(size_t)r * nheads + h] = pd[p];
                    }
                }
            }
        }
    }
}

// ---------------------------------------------------------------------------
// Final MFMA GEMM over concat [bn1(h1)|bn2(h2)|bn3(h3)] (K=768) with packed
// l2_W (40 cols zero-padded to 64), fused bias + log_softmax. out fp32 [M,40].
// ---------------------------------------------------------------------------
__launch_bounds__(256)
__global__ void k_mfinal(const u16* __restrict__ h1, const u16* __restrict__ h2,
                         const u16* __restrict__ h3,
                         const float* __restrict__ scale, const float* __restrict__ shift,
                         const u16* __restrict__ pb, const float* __restrict__ bias,
                         float* __restrict__ out, int M)
{
    const int tid = threadIdx.x;
    const int w = tid >> 6, l = tid & 63;
    const int lo = l & 15, hi = l >> 4;
    const int row0 = blockIdx.x * 64 + w * 16;
    if (row0 >= M) return;
    const int K5 = 24;   // 768/32

    f32x4 acc[4];
    #pragma unroll
    for (int i = 0; i < 4; ++i) acc[i] = (f32x4){0.f, 0.f, 0.f, 0.f};

    int arow = row0 + lo; if (arow >= M) arow = M - 1;

    for (int k5 = 0; k5 < K5; ++k5) {
        const int kk = k5 * 32 + hi * 8;   // region-uniform per k5 (32-aligned splits)
        const u16* src; int ld, offk;
        if (kk < 128)      { src = h1; ld = 128; offk = kk; }
        else if (kk < 640) { src = h2; ld = 512; offk = kk - 128; }
        else               { src = h3; ld = 128; offk = kk - 640; }
        uint4 q = *reinterpret_cast<const uint4*>(src + (size_t)arow * ld + offk);
        float x[8];
        bf2x(q.x, x[0], x[1]); bf2x(q.y, x[2], x[3]);
        bf2x(q.z, x[4], x[5]); bf2x(q.w, x[6], x[7]);
        #pragma unroll
        for (int j = 0; j < 8; ++j) x[j] = fmaf(x[j], scale[kk + j], shift[kk + j]);
        U8 au;
        au.q.x = packbf(x[0], x[1]); au.q.y = packbf(x[2], x[3]);
        au.q.z = packbf(x[4], x[5]); au.q.w = packbf(x[6], x[7]);
        s16x8 af = au.v;
        #pragma unroll
        for (int cb = 0; cb < 4; ++cb) {
            s16x8 bf = *reinterpret_cast<const s16x8*>(pb + ((size_t)cb * K5 + k5) * 512 + l * 8);
            acc[cb] = __builtin_amdgcn_mfma_f32_16x16x32_bf16(af, bf, acc[cb], 0, 0, 0);
        }
    }

    // bias + log_softmax over 40 valid cols (cb2 valid iff lo<8; cb3 all pad)
    #pragma unroll
    for (int p = 0; p < 4; ++p) {
        int r = row0 + hi * 4 + p;
        float z0 = acc[0][p] + bias[lo];
        float z1 = acc[1][p] + bias[16 + lo];
        float z2 = -INF_F;
        if (lo < 8) z2 = acc[2][p] + bias[32 + lo];
        float mx = fmaxf(fmaxf(z0, z1), z2);
        #pragma unroll
        for (int m = 1; m < 16; m <<= 1) mx = fmaxf(mx, __shfl_xor(mx, m, 64));
        float se = __expf(z0 - mx) + __expf(z1 - mx) + ((lo < 8) ? __expf(z2 - mx) : 0.f);
        #pragma unroll
        for (int m = 1; m < 16; m <<= 1) se += __shfl_xor(se, m, 64);
        float lse = mx + __logf(se);
        if (r < M) {
            out[(size_t)r * 40 + lo]      = z0 - lse;
            out[(size_t)r * 40 + 16 + lo] = z1 - lse;
            if (lo < 8) out[(size_t)r * 40 + 32 + lo] = z2 - lse;
        }
    }
}

// ---------------------------------------------------------------------------
// BN stats stage 1: per-block column partial sums/sumsq of bf16 matrix.
// ---------------------------------------------------------------------------
__launch_bounds__(256)
__global__ void k_colstats(const u16* __restrict__ X, int M, int C,
                           float* __restrict__ psum, float* __restrict__ psq)
{
    const int CG  = C >> 3;
    const int RPI = 256 / CG;
    const int tid = threadIdx.x;
    const int cg  = tid & (CG - 1);
    const int ro  = tid / CG;
    const int nb  = gridDim.x;
    const int rows_chunk = (M + nb - 1) / nb;
    const int r0 = blockIdx.x * rows_chunk;
    const int r1 = min(M, r0 + rows_chunk);

    float s[8] = {}, q[8] = {};
    for (int r = r0 + ro; r < r1; r += RPI) {
        uint4 u = *reinterpret_cast<const uint4*>(X + (size_t)r * C + cg * 8);
        float x[8];
        bf2x(u.x, x[0], x[1]); bf2x(u.y, x[2], x[3]);
        bf2x(u.z, x[4], x[5]); bf2x(u.w, x[6], x[7]);
        #pragma unroll
        for (int j = 0; j < 8; ++j) { s[j] += x[j]; q[j] = fmaf(x[j], x[j], q[j]); }
    }

    __shared__ float lsum[8][256];
    __shared__ float lsq [8][256];
    #pragma unroll
    for (int j = 0; j < 8; ++j) { lsum[j][tid] = s[j]; lsq[j][tid] = q[j]; }
    __syncthreads();

    if (tid < CG) {
        #pragma unroll
        for (int j = 0; j < 8; ++j) {
            float ss = 0.f, qq = 0.f;
            for (int o = 0; o < RPI; ++o) {
                ss += lsum[j][o * CG + tid];
                qq += lsq [j][o * CG + tid];
            }
            psum[(size_t)blockIdx.x * C + tid * 8 + j] = ss;
            psq [(size_t)blockIdx.x * C + tid * 8 + j] = qq;
        }
    }
}

__launch_bounds__(256)
__global__ void k_colred(const float* __restrict__ psum, const float* __restrict__ psq,
                         const float* __restrict__ g, const float* __restrict__ b,
                         int nb, int M, int C,
                         float* __restrict__ scale, float* __restrict__ shift)
{
    int c = blockIdx.x * 4 + (threadIdx.x >> 6);
    int lane = threadIdx.x & 63;
    if (c >= C) return;
    float s = 0.f, q = 0.f;
    for (int l = lane; l < nb; l += 64) {
        s += psum[(size_t)l * C + c];
        q += psq [(size_t)l * C + c];
    }
    #pragma unroll
    for (int off = 32; off; off >>= 1) {
        s += __shfl_xor(s, off, 64);
        q += __shfl_xor(q, off, 64);
    }
    if (lane == 0) {
        float mu  = s / (float)M;
        float var = q / (float)M - mu * mu;
        float sc  = g[c] * rsqrtf(var + 1e-5f);
        scale[c] = sc;
        shift[c] = b[c] - mu * sc;
    }
}

// ---------------------------------------------------------------------------
// CSR build: count -> scan -> scatter
// ---------------------------------------------------------------------------
__launch_bounds__(256)
__global__ void k_count(const int* __restrict__ dst, int E, int* __restrict__ counts)
{
    int e = blockIdx.x * 256 + threadIdx.x;
    if (e < E) atomicAdd(&counts[dst[e]], 1);
}

__launch_bounds__(1024)
__global__ void k_scan(const int* __restrict__ counts, int* __restrict__ rowstart, int n)
{
    __shared__ int wsum[16];
    __shared__ int s_carry;
    int tid = threadIdx.x, lane = tid & 63, w = tid >> 6;
    if (tid == 0) { s_carry = 0; rowstart[0] = 0; }
    __syncthreads();
    for (int base = 0; base < n; base += 1024) {
        int carry = s_carry;
        int v = (base + tid < n) ? counts[base + tid] : 0;
        int x = v;
        #pragma unroll
        for (int off = 1; off < 64; off <<= 1) {
            int t = __shfl_up(x, off, 64);
            if (lane >= off) x += t;
        }
        if (lane == 63) wsum[w] = x;
        __syncthreads();
        int woff = 0;
        #pragma unroll
        for (int i = 0; i < 16; ++i)
            if (i < w) woff += wsum[i];
        int incl = carry + woff + x;
        if (base + tid < n) rowstart[base + tid + 1] = incl;
        __syncthreads();
        if (tid == 1023) s_carry = incl;
        __syncthreads();
    }
}

__launch_bounds__(256)
__global__ void k_scatter(const int* __restrict__ ei, int E,
                          const int* __restrict__ rowstart,
                          int* __restrict__ fill, int* __restrict__ csr)
{
    int e = blockIdx.x * 256 + threadIdx.x;
    if (e >= E) return;
    int s = ei[e], d = ei[E + e];
    int pos = rowstart[d] + atomicAdd(&fill[d], 1);
    csr[pos] = s;
}

// ---------------------------------------------------------------------------
// GAT aggregation, HEADS=4, TWO-PASS softmax, depth-4 prefetch / unroll-2.
// One wave per dst covers all heads; lane l: head=l>>4, dims (l&15)*8..+8.
// Pass 1: per-head max lane-parallel. Pass 2: no rescale -> independent FMAs,
// 4 row-gathers in flight per wave (MLP), 2 edges consumed per iteration.
// ---------------------------------------------------------------------------
__launch_bounds__(256)
__global__ void k_gat_agg_h4(const u16* __restrict__ hp,
                             const float* __restrict__ as_, const float* __restrict__ ad_,
                             const int* __restrict__ rowstart, const int* __restrict__ csr,
                             const float* __restrict__ bias, u16* __restrict__ out, int Nn)
{
    int d = (int)((blockIdx.x * (size_t)blockDim.x + threadIdx.x) >> 6);
    int lane = threadIdx.x & 63;
    if (d >= Nn) return;
    const int h = lane >> 4;
    const int li = lane & 15;
    const int dim = li * 8;
    int e0 = rowstart[d], e1 = rowstart[d + 1];
    float adv = ad_[(size_t)d * 4 + h];

    // ---- pass 1: per-head max (16 lanes per head stride the edge list) ----
    float mx = -INF_F;
    for (int j = e0 + li; j < e1; j += 16) {
        int s = csr[j];
        float e = as_[(size_t)s * 4 + h] + adv;
        e = e >= 0.f ? e : 0.2f * e;
        mx = fmaxf(mx, e);
    }
    #pragma unroll
    for (int m = 1; m < 16; m <<= 1) mx = fmaxf(mx, __shfl_xor(mx, m, 64));

    // ---- pass 2: depth-4 prefetch, unroll-2, no rescale ----
    float lsum = 0.f;
    float acc[8] = {};

    #define FETCH4(J, A, U) { int jj = min((J), e1 - 1); int s_ = csr[jj];            \
        A = as_[(size_t)s_ * 4 + h];                                                  \
        U = *reinterpret_cast<const uint4*>(hp + ((size_t)s_ * 4 + h) * 128 + dim); }
    #define CONSUME4(A, U) { float e_ = A + adv; e_ = e_ >= 0.f ? e_ : 0.2f * e_;     \
        float w_ = __expf(e_ - mx); lsum += w_;                                       \
        float x_[8];                                                                  \
        bf2x(U.x, x_[0], x_[1]); bf2x(U.y, x_[2], x_[3]);                             \
        bf2x(U.z, x_[4], x_[5]); bf2x(U.w, x_[6], x_[7]);                             \
        _Pragma("unroll")                                                             \
        for (int t_ = 0; t_ < 8; ++t_) acc[t_] = fmaf(x_[t_], w_, acc[t_]); }

    float a0, a1, a2, a3;
    uint4 u0, u1, u2, u3;
    FETCH4(e0 + 0, a0, u0);
    FETCH4(e0 + 1, a1, u1);
    FETCH4(e0 + 2, a2, u2);
    FETCH4(e0 + 3, a3, u3);

    int j = e0;
    for (; j + 1 < e1; j += 2) {
        CONSUME4(a0, u0);
        CONSUME4(a1, u1);
        a0 = a2; u0 = u2; a1 = a3; u1 = u3;
        FETCH4(j + 4, a2, u2);
        FETCH4(j + 5, a3, u3);
    }
    if (j < e1) CONSUME4(a0, u0);
    #undef FETCH4
    #undef CONSUME4

    float inv = 1.f / (lsum + 1e-16f);
    const int ob = h * 128 + dim;
    float v[8];
    #pragma unroll
    for (int t = 0; t < 8; ++t) {
        float z = acc[t] * inv + bias[ob + t];
        v[t] = z >= 0.f ? z : 0.01f * z;
    }
    uint4 o;
    o.x = packbf(v[0], v[1]); o.y = packbf(v[2], v[3]);
    o.z = packbf(v[4], v[5]); o.w = packbf(v[6], v[7]);
    *reinterpret_cast<uint4*>(out + (size_t)d * 512 + ob) = o;
}

// ---------------------------------------------------------------------------
// GAT aggregation, HEADS=1, TWO-PASS softmax, depth-4 prefetch / unroll-2.
// ---------------------------------------------------------------------------
__launch_bounds__(256)
__global__ void k_gat_agg_h1(const u16* __restrict__ hp,
                             const float* __restrict__ as_, const float* __restrict__ ad_,
                             const int* __restrict__ rowstart, const int* __restrict__ csr,
                             const float* __restrict__ bias, u16* __restrict__ out, int Nn)
{
    int d = (int)((blockIdx.x * (size_t)blockDim.x + threadIdx.x) >> 6);
    int lane = threadIdx.x & 63;
    if (d >= Nn) return;
    const int dim = lane * 2;
    int e0 = rowstart[d], e1 = rowstart[d + 1];
    float adv = ad_[d];

    // ---- pass 1: max, all 64 lanes stride edges ----
    float mx = -INF_F;
    for (int j = e0 + lane; j < e1; j += 64) {
        int s = csr[j];
        float e = as_[s] + adv;
        e = e >= 0.f ? e : 0.2f * e;
        mx = fmaxf(mx, e);
    }
    #pragma unroll
    for (int m = 1; m < 64; m <<= 1) mx = fmaxf(mx, __shfl_xor(mx, m, 64));

    // ---- pass 2: depth-4 prefetch, unroll-2 ----
    float lsum = 0.f, acc0 = 0.f, acc1 = 0.f;

    #define FETCH1(J, A, U) { int jj = min((J), e1 - 1); int s_ = csr[jj];            \
        A = as_[s_];                                                                  \
        U = *reinterpret_cast<const unsigned int*>(hp + (size_t)s_ * 128 + dim); }
    #define CONSUME1(A, U) { float e_ = A + adv; e_ = e_ >= 0.f ? e_ : 0.2f * e_;     \
        float w_ = __expf(e_ - mx); float x0_, x1_; bf2x(U, x0_, x1_);                \
        lsum += w_; acc0 = fmaf(x0_, w_, acc0); acc1 = fmaf(x1_, w_, acc1); }

    float a0, a1, a2, a3;
    unsigned int u0, u1, u2, u3;
    FETCH1(e0 + 0, a0, u0);
    FETCH1(e0 + 1, a1, u1);
    FETCH1(e0 + 2, a2, u2);
    FETCH1(e0 + 3, a3, u3);

    int j = e0;
    for (; j + 1 < e1; j += 2) {
        CONSUME1(a0, u0);
        CONSUME1(a1, u1);
        a0 = a2; u0 = u2; a1 = a3; u1 = u3;
        FETCH1(j + 4, a2, u2);
        FETCH1(j + 5, a3, u3);
    }
    if (j < e1) CONSUME1(a0, u0);
    #undef FETCH1
    #undef CONSUME1

    float inv = 1.f / (lsum + 1e-16f);
    float v0 = acc0 * inv + bias[dim];
    float v1 = acc1 * inv + bias[dim + 1];
    v0 = v0 >= 0.f ? v0 : 0.01f * v0;
    v1 = v1 >= 0.f ? v1 : 0.01f * v1;
    *reinterpret_cast<unsigned int*>(out + (size_t)d * 128 + dim) = packbf(v0, v1);
}

// ---------------------------------------------------------------------------
extern "C" void kernel_launch(void* const* d_in, const int* in_sizes, int n_in,
                              void* d_out, int out_size, void* d_ws, size_t ws_size,
                              hipStream_t stream)
{
    const float* x     = (const float*)d_in[0];
    const int*   ei    = (const int*)  d_in[1];
    const float* fw_W  = (const float*)d_in[2];
    const float* fw_b  = (const float*)d_in[3];
    const float* c1_W  = (const float*)d_in[4];
    const float* c1_as = (const float*)d_in[5];
    const float* c1_ad = (const float*)d_in[6];
    const float* c1_b  = (const float*)d_in[7];
    const float* c2_W  = (const float*)d_in[8];
    const float* c2_as = (const float*)d_in[9];
    const float* c2_ad = (const float*)d_in[10];
    const float* c2_b  = (const float*)d_in[11];
    const float* bn1_g = (const float*)d_in[12];
    const float* bn1_b = (const float*)d_in[13];
    const float* bn2_g = (const float*)d_in[14];
    const float* bn2_b = (const float*)d_in[15];
    const float* bn3_g = (const float*)d_in[16];
    const float* bn3_b = (const float*)d_in[17];
    const float* l2_W  = (const float*)d_in[18];
    const float* l2_b  = (const float*)d_in[19];
    float* out = (float*)d_out;

    const int N = in_sizes[0] / 256;   // 50000
    const int E = in_sizes[1] / 2;     // 850000
    const int NB = 256;

    char* base = (char*)d_ws;
    size_t off = 0;
    auto alloc = [&](size_t bytes) -> void* {
        void* p = (void*)(base + off);
        off = (off + bytes + 255) & ~(size_t)255;
        return p;
    };
    // --- zeroed region (counts, fill) ---
    int*   counts = (int*)  alloc((size_t)N * 4);
    int*   fill   = (int*)  alloc((size_t)N * 4);
    size_t zero_bytes = off;
    // --- rest ---
    float* as1      = (float*)alloc((size_t)N * 4 * 4);
    float* ad1      = (float*)alloc((size_t)N * 4 * 4);
    float* as2      = (float*)alloc((size_t)N * 4);
    float* ad2      = (float*)alloc((size_t)N * 4);
    float* psum     = (float*)alloc((size_t)NB * 512 * 4);
    float* psq      = (float*)alloc((size_t)NB * 512 * 4);
    int*   rowstart = (int*)  alloc((size_t)(N + 1) * 4);
    int*   csr      = (int*)  alloc((size_t)E * 4);
    float* scale768 = (float*)alloc(768 * 4);
    float* shift768 = (float*)alloc(768 * 4);
    u16*   pb_l1    = (u16*)  alloc((size_t)256 * 128 * 2);
    u16*   pb_c1    = (u16*)  alloc((size_t)128 * 512 * 2);
    u16*   pb_c2    = (u16*)  alloc((size_t)512 * 128 * 2);
    u16*   pb_f     = (u16*)  alloc((size_t)768 * 64 * 2);
    u16*   h1       = (u16*)  alloc((size_t)N * 128 * 2);
    u16*   h2       = (u16*)  alloc((size_t)N * 512 * 2);
    u16*   hp1      = (u16*)  alloc((size_t)N * 512 * 2);  // dead after agg1:
    u16*   hp2      = hp1;                                  //  reuse for hp2 [N,128]
    u16*   h3       = hp1 + (size_t)N * 128;                //  and h3 [N,128]
    (void)ws_size; (void)n_in; (void)out_size;

    const int mb = (N + 63) / 64;
    const int wave_blocks = (int)(((size_t)N * 64 + 255) / 256);

    hipMemsetAsync(base, 0, zero_bytes, stream);

    // pack weights into MFMA-B layout (tiny)
    k_packB<<<(256 * 128 + 255) / 256, 256, 0, stream>>>(fw_W, 256, 128, 128, pb_l1);
    k_packB<<<(128 * 512 + 255) / 256, 256, 0, stream>>>(c1_W, 128, 512, 512, pb_c1);
    k_packB<<<(512 * 128 + 255) / 256, 256, 0, stream>>>(c2_W, 512, 128, 128, pb_c2);
    k_packB<<<(768 *  64 + 255) / 256, 256, 0, stream>>>(l2_W, 768,  40,  64, pb_f);

    // CSR build (independent)
    k_count<<<(E + 255) / 256, 256, 0, stream>>>(ei + E, E, counts);
    k_scan<<<1, 1024, 0, stream>>>(counts, rowstart, N);
    k_scatter<<<(E + 255) / 256, 256, 0, stream>>>(ei, E, rowstart, fill, csr);

    // layer 1: h1 = lrelu(x @ fw_W + fw_b)
    k_mgemm<8, true, false, true, true, 0><<<dim3(1, mb), 256, 0, stream>>>(
        x, 256, 256, pb_l1, h1, 128, N, nullptr, nullptr, fw_b,
        nullptr, nullptr, nullptr, nullptr, 0);

    // BN1
    k_colstats<<<NB, 256, 0, stream>>>(h1, N, 128, psum, psq);
    k_colred<<<(128 + 3) / 4, 256, 0, stream>>>(psum, psq, bn1_g, bn1_b, NB, N, 128,
                                                scale768, shift768);

    // conv1 projection: hp1 = bn1(h1) @ c1_W [N,512] + fused alpha (2 heads/block)
    k_mgemm<16, false, true, false, false, 2><<<dim3(2, mb), 256, 0, stream>>>(
        h1, 128, 128, pb_c1, hp1, 512, N, scale768, shift768, nullptr,
        c1_as, c1_ad, as1, ad1, 4);
    k_gat_agg_h4<<<wave_blocks, 256, 0, stream>>>(
        hp1, as1, ad1, rowstart, csr, c1_b, h2, N);

    // BN2
    k_colstats<<<NB, 256, 0, stream>>>(h2, N, 512, psum, psq);
    k_colred<<<(512 + 3) / 4, 256, 0, stream>>>(psum, psq, bn2_g, bn2_b, NB, N, 512,
                                                scale768 + 128, shift768 + 128);

    // conv2 projection: hp2 = bn2(h2) @ c2_W [N,128] + fused alpha (1 head)
    k_mgemm<8, false, true, false, false, 1><<<dim3(1, mb), 256, 0, stream>>>(
        h2, 512, 512, pb_c2, hp2, 128, N, scale768 + 128, shift768 + 128, nullptr,
        c2_as, c2_ad, as2, ad2, 1);
    k_gat_agg_h1<<<wave_blocks, 256, 0, stream>>>(
        hp2, as2, ad2, rowstart, csr, c2_b, h3, N);

    // BN3
    k_colstats<<<NB, 256, 0, stream>>>(h3, N, 128, psum, psq);
    k_colred<<<(128 + 3) / 4, 256, 0, stream>>>(psum, psq, bn3_g, bn3_b, NB, N, 128,
                                                scale768 + 640, shift768 + 640);

    // final fused GEMM + log_softmax
    k_mfinal<<<mb, 256, 0, stream>>>(h1, h2, h3, scale768, shift768, pb_f, l2_b, out, N);
}

// Round 9
// 546.373 us; speedup vs baseline: 1.0938x; 1.0223x over previous
//
#include <hip/hip_runtime.h>

#define INF_F __builtin_inff()

typedef unsigned short u16;
typedef __attribute__((ext_vector_type(8))) short s16x8;   // 8 bf16 (4 VGPRs)
typedef __attribute__((ext_vector_type(4))) float f32x4;   // MFMA accum

union U8 { uint4 q; s16x8 v; };

__device__ __forceinline__ float b2f(u16 u) {
    union { unsigned int i; float f; } v; v.i = ((unsigned int)u) << 16; return v.f;
}
__device__ __forceinline__ u16 f2b(float f) {
    union { float f; unsigned int i; } v; v.f = f;
    unsigned int r = (v.i + 0x7FFFu + ((v.i >> 16) & 1u)) >> 16;
    return (u16)r;
}
__device__ __forceinline__ void bf2x(unsigned int p, float& lo, float& hi) {
    union { unsigned int i; float f; } a, b;
    a.i = p << 16; b.i = p & 0xFFFF0000u;
    lo = a.f; hi = b.f;
}
__device__ __forceinline__ unsigned int packbf(float lo, float hi) {
    return (unsigned int)f2b(lo) | ((unsigned int)f2b(hi) << 16);
}

// ---------------------------------------------------------------------------
// k_prep: pack all 4 weights into bf16 MFMA-B layout + edge degree count,
// one launch. Packed (k,n) -> pb[((n>>4)*(K/32)+(k>>5))*512 + ((k>>3)&3)*128
//                               + (n&15)*8 + (k&7)]; pad cols (n>=N) are 0.
// ---------------------------------------------------------------------------
__device__ __forceinline__ void pack_one(const float* __restrict__ W, int K, int N,
                                         int Npad, u16* __restrict__ pb, int idx)
{
    int k = idx / Npad, n = idx - k * Npad;
    float v = (n < N) ? W[(size_t)k * N + n] : 0.f;
    int K5 = K >> 5;
    size_t o = ((size_t)(n >> 4) * K5 + (k >> 5)) * 512
             + ((size_t)((k >> 3) & 3)) * 128 + (n & 15) * 8 + (k & 7);
    pb[o] = f2b(v);
}

__launch_bounds__(256)
__global__ void k_prep(const float* __restrict__ fw_W, const float* __restrict__ c1_W,
                       const float* __restrict__ c2_W, const float* __restrict__ l2_W,
                       u16* __restrict__ pb_l1, u16* __restrict__ pb_c1,
                       u16* __restrict__ pb_c2, u16* __restrict__ pb_f,
                       const int* __restrict__ dst, int E, int* __restrict__ counts)
{
    int idx = blockIdx.x * 256 + threadIdx.x;
    if (idx < 32768) { pack_one(fw_W, 256, 128, 128, pb_l1, idx); return; }
    idx -= 32768;
    if (idx < 65536) { pack_one(c1_W, 128, 512, 512, pb_c1, idx); return; }
    idx -= 65536;
    if (idx < 65536) { pack_one(c2_W, 512, 128, 128, pb_c2, idx); return; }
    idx -= 65536;
    if (idx < 49152) { pack_one(l2_W, 768, 40, 64, pb_f, idx); return; }
    idx -= 49152;
    if (idx < E) atomicAdd(&counts[dst[idx]], 1);
}

// ---------------------------------------------------------------------------
// MFMA GEMM: C(bf16) = act(A' @ B [+bias]); A'[r,k]=A[r,k]*scale[k]+shift[k].
// No LDS / no barriers: wave w owns rows [row0+16w,+16); B frags read from
// packed pb (L2-resident); A frag = one 16B(bf16)/32B(fp32) load per lane.
// HEADS_PB>0: fused GAT alpha epilogue (head width = 128 cols, deterministic).
// ---------------------------------------------------------------------------
template<int NFRAG, bool A_FP32, bool BN_A, bool BIAS, bool LRELU, int HEADS_PB>
__launch_bounds__(256)
__global__ void k_mgemm(const void* __restrict__ Av, int lda, int K,
                        const u16* __restrict__ pb,
                        u16* __restrict__ C, int ldc, int M,
                        const float* __restrict__ scale, const float* __restrict__ shift,
                        const float* __restrict__ bias,
                        const float* __restrict__ aw_s, const float* __restrict__ aw_d,
                        float* __restrict__ as_o, float* __restrict__ ad_o, int nheads)
{
    const int tid = threadIdx.x;
    const int w = tid >> 6, l = tid & 63;
    const int lo = l & 15, hi = l >> 4;
    const int row0 = blockIdx.y * 64 + w * 16;
    if (row0 >= M) return;
    const int cb0 = blockIdx.x * NFRAG;
    const int K5 = K >> 5;

    f32x4 acc[NFRAG];
    #pragma unroll
    for (int i = 0; i < NFRAG; ++i) acc[i] = (f32x4){0.f, 0.f, 0.f, 0.f};

    int arow = row0 + lo; if (arow >= M) arow = M - 1;

    for (int k5 = 0; k5 < K5; ++k5) {
        const int ak = k5 * 32 + hi * 8;
        float x[8];
        if (A_FP32) {
            const float* A = (const float*)Av + (size_t)arow * lda + ak;
            float4 v0 = *reinterpret_cast<const float4*>(A);
            float4 v1 = *reinterpret_cast<const float4*>(A + 4);
            x[0]=v0.x; x[1]=v0.y; x[2]=v0.z; x[3]=v0.w;
            x[4]=v1.x; x[5]=v1.y; x[6]=v1.z; x[7]=v1.w;
        } else {
            uint4 q = *reinterpret_cast<const uint4*>((const u16*)Av + (size_t)arow * lda + ak);
            bf2x(q.x, x[0], x[1]); bf2x(q.y, x[2], x[3]);
            bf2x(q.z, x[4], x[5]); bf2x(q.w, x[6], x[7]);
        }
        if (BN_A) {
            #pragma unroll
            for (int j = 0; j < 8; ++j) x[j] = fmaf(x[j], scale[ak + j], shift[ak + j]);
        }
        U8 au;
        au.q.x = packbf(x[0], x[1]); au.q.y = packbf(x[2], x[3]);
        au.q.z = packbf(x[4], x[5]); au.q.w = packbf(x[6], x[7]);
        s16x8 af = au.v;
        #pragma unroll
        for (int cb = 0; cb < NFRAG; ++cb) {
            s16x8 bf = *reinterpret_cast<const s16x8*>(
                pb + ((size_t)(cb0 + cb) * K5 + k5) * 512 + l * 8);
            acc[cb] = __builtin_amdgcn_mfma_f32_16x16x32_bf16(af, bf, acc[cb], 0, 0, 0);
        }
    }

    // C store: D lane layout col=lo, row=hi*4+p
    #pragma unroll
    for (int cb = 0; cb < NFRAG; ++cb) {
        int col = (cb0 + cb) * 16 + lo;
        #pragma unroll
        for (int p = 0; p < 4; ++p) {
            int r = row0 + hi * 4 + p;
            if (r < M) {
                float v = acc[cb][p];
                if (BIAS)  v += bias[col];
                if (LRELU) v = v >= 0.f ? v : 0.01f * v;
                C[(size_t)r * ldc + col] = f2b(v);
            }
        }
    }

    if (HEADS_PB > 0) {
        const int CBH = NFRAG / HEADS_PB;   // 8 col-frags per head (head width 128)
        #pragma unroll
        for (int hl = 0; hl < HEADS_PB; ++hl) {
            float ps[4] = {0.f,0.f,0.f,0.f}, pd[4] = {0.f,0.f,0.f,0.f};
            #pragma unroll
            for (int cc = 0; cc < CBH; ++cc) {
                int cb = hl * CBH + cc;
                int col = (cb0 + cb) * 16 + lo;
                float ws = aw_s[col], wd = aw_d[col];
                #pragma unroll
                for (int p = 0; p < 4; ++p) {
                    ps[p] = fmaf(acc[cb][p], ws, ps[p]);
                    pd[p] = fmaf(acc[cb][p], wd, pd[p]);
                }
            }
            #pragma unroll
            for (int m = 1; m < 16; m <<= 1) {
                #pragma unroll
                for (int p = 0; p < 4; ++p) {
                    ps[p] += __shfl_xor(ps[p], m, 64);
                    pd[p] += __shfl_xor(pd[p], m, 64);
                }
            }
            if (lo == 0) {
                int h = (cb0 >> 3) + hl;
                #pragma unroll
                for (int p = 0; p < 4; ++p) {
                    int r = row0 + hi * 4 + p;
                    if (r < M) {
                        as_o[(size_t)r * nheads + h] = ps[p];
                        ad_o[(size_t)r * nheads + h] = pd[p];
                    }
                }
            }
        }
    }
}

// ---------------------------------------------------------------------------
// Final MFMA GEMM over concat [bn1(h1)|bn2(h2)|bn3(h3)] (K=768) with packed
// l2_W (40 cols zero-padded to 64), fused bias + log_softmax. out fp32 [M,40].
// ---------------------------------------------------------------------------
__launch_bounds__(256)
__global__ void k_mfinal(const u16* __restrict__ h1, const u16* __restrict__ h2,
                         const u16* __restrict__ h3,
                         const float* __restrict__ scale, const float* __restrict__ shift,
                         const u16* __restrict__ pb, const float* __restrict__ bias,
                         float* __restrict__ out, int M)
{
    const int tid = threadIdx.x;
    const int w = tid >> 6, l = tid & 63;
    const int lo = l & 15, hi = l >> 4;
    const int row0 = blockIdx.x * 64 + w * 16;
    if (row0 >= M) return;
    const int K5 = 24;   // 768/32

    f32x4 acc[4];
    #pragma unroll
    for (int i = 0; i < 4; ++i) acc[i] = (f32x4){0.f, 0.f, 0.f, 0.f};

    int arow = row0 + lo; if (arow >= M) arow = M - 1;

    for (int k5 = 0; k5 < K5; ++k5) {
        const int kk = k5 * 32 + hi * 8;   // region-uniform per k5 (32-aligned splits)
        const u16* src; int ld, offk;
        if (kk < 128)      { src = h1; ld = 128; offk = kk; }
        else if (kk < 640) { src = h2; ld = 512; offk = kk - 128; }
        else               { src = h3; ld = 128; offk = kk - 640; }
        uint4 q = *reinterpret_cast<const uint4*>(src + (size_t)arow * ld + offk);
        float x[8];
        bf2x(q.x, x[0], x[1]); bf2x(q.y, x[2], x[3]);
        bf2x(q.z, x[4], x[5]); bf2x(q.w, x[6], x[7]);
        #pragma unroll
        for (int j = 0; j < 8; ++j) x[j] = fmaf(x[j], scale[kk + j], shift[kk + j]);
        U8 au;
        au.q.x = packbf(x[0], x[1]); au.q.y = packbf(x[2], x[3]);
        au.q.z = packbf(x[4], x[5]); au.q.w = packbf(x[6], x[7]);
        s16x8 af = au.v;
        #pragma unroll
        for (int cb = 0; cb < 4; ++cb) {
            s16x8 bf = *reinterpret_cast<const s16x8*>(pb + ((size_t)cb * K5 + k5) * 512 + l * 8);
            acc[cb] = __builtin_amdgcn_mfma_f32_16x16x32_bf16(af, bf, acc[cb], 0, 0, 0);
        }
    }

    // bias + log_softmax over 40 valid cols (cb2 valid iff lo<8; cb3 all pad)
    #pragma unroll
    for (int p = 0; p < 4; ++p) {
        int r = row0 + hi * 4 + p;
        float z0 = acc[0][p] + bias[lo];
        float z1 = acc[1][p] + bias[16 + lo];
        float z2 = -INF_F;
        if (lo < 8) z2 = acc[2][p] + bias[32 + lo];
        float mx = fmaxf(fmaxf(z0, z1), z2);
        #pragma unroll
        for (int m = 1; m < 16; m <<= 1) mx = fmaxf(mx, __shfl_xor(mx, m, 64));
        float se = __expf(z0 - mx) + __expf(z1 - mx) + ((lo < 8) ? __expf(z2 - mx) : 0.f);
        #pragma unroll
        for (int m = 1; m < 16; m <<= 1) se += __shfl_xor(se, m, 64);
        float lse = mx + __logf(se);
        if (r < M) {
            out[(size_t)r * 40 + lo]      = z0 - lse;
            out[(size_t)r * 40 + 16 + lo] = z1 - lse;
            if (lo < 8) out[(size_t)r * 40 + 32 + lo] = z2 - lse;
        }
    }
}

// ---------------------------------------------------------------------------
// BN stats stage 1: per-block column partial sums/sumsq of bf16 matrix.
// ---------------------------------------------------------------------------
__launch_bounds__(256)
__global__ void k_colstats(const u16* __restrict__ X, int M, int C,
                           float* __restrict__ psum, float* __restrict__ psq)
{
    const int CG  = C >> 3;
    const int RPI = 256 / CG;
    const int tid = threadIdx.x;
    const int cg  = tid & (CG - 1);
    const int ro  = tid / CG;
    const int nb  = gridDim.x;
    const int rows_chunk = (M + nb - 1) / nb;
    const int r0 = blockIdx.x * rows_chunk;
    const int r1 = min(M, r0 + rows_chunk);

    float s[8] = {}, q[8] = {};
    for (int r = r0 + ro; r < r1; r += RPI) {
        uint4 u = *reinterpret_cast<const uint4*>(X + (size_t)r * C + cg * 8);
        float x[8];
        bf2x(u.x, x[0], x[1]); bf2x(u.y, x[2], x[3]);
        bf2x(u.z, x[4], x[5]); bf2x(u.w, x[6], x[7]);
        #pragma unroll
        for (int j = 0; j < 8; ++j) { s[j] += x[j]; q[j] = fmaf(x[j], x[j], q[j]); }
    }

    __shared__ float lsum[8][256];
    __shared__ float lsq [8][256];
    #pragma unroll
    for (int j = 0; j < 8; ++j) { lsum[j][tid] = s[j]; lsq[j][tid] = q[j]; }
    __syncthreads();

    if (tid < CG) {
        #pragma unroll
        for (int j = 0; j < 8; ++j) {
            float ss = 0.f, qq = 0.f;
            for (int o = 0; o < RPI; ++o) {
                ss += lsum[j][o * CG + tid];
                qq += lsq [j][o * CG + tid];
            }
            psum[(size_t)blockIdx.x * C + tid * 8 + j] = ss;
            psq [(size_t)blockIdx.x * C + tid * 8 + j] = qq;
        }
    }
}

__launch_bounds__(256)
__global__ void k_colred(const float* __restrict__ psum, const float* __restrict__ psq,
                         const float* __restrict__ g, const float* __restrict__ b,
                         int nb, int M, int C,
                         float* __restrict__ scale, float* __restrict__ shift)
{
    int c = blockIdx.x * 4 + (threadIdx.x >> 6);
    int lane = threadIdx.x & 63;
    if (c >= C) return;
    float s = 0.f, q = 0.f;
    for (int l = lane; l < nb; l += 64) {
        s += psum[(size_t)l * C + c];
        q += psq [(size_t)l * C + c];
    }
    #pragma unroll
    for (int off = 32; off; off >>= 1) {
        s += __shfl_xor(s, off, 64);
        q += __shfl_xor(q, off, 64);
    }
    if (lane == 0) {
        float mu  = s / (float)M;
        float var = q / (float)M - mu * mu;
        float sc  = g[c] * rsqrtf(var + 1e-5f);
        scale[c] = sc;
        shift[c] = b[c] - mu * sc;
    }
}

// ---------------------------------------------------------------------------
// Single-block scan: counts -> rowstart (exclusive prefix).
// ---------------------------------------------------------------------------
__launch_bounds__(1024)
__global__ void k_scan(const int* __restrict__ counts, int* __restrict__ rowstart, int n)
{
    __shared__ int wsum[16];
    __shared__ int s_carry;
    int tid = threadIdx.x, lane = tid & 63, w = tid >> 6;
    if (tid == 0) { s_carry = 0; rowstart[0] = 0; }
    __syncthreads();
    for (int base = 0; base < n; base += 1024) {
        int carry = s_carry;
        int v = (base + tid < n) ? counts[base + tid] : 0;
        int x = v;
        #pragma unroll
        for (int off = 1; off < 64; off <<= 1) {
            int t = __shfl_up(x, off, 64);
            if (lane >= off) x += t;
        }
        if (lane == 63) wsum[w] = x;
        __syncthreads();
        int woff = 0;
        #pragma unroll
        for (int i = 0; i < 16; ++i)
            if (i < w) woff += wsum[i];
        int incl = carry + woff + x;
        if (base + tid < n) rowstart[base + tid + 1] = incl;
        __syncthreads();
        if (tid == 1023) s_carry = incl;
        __syncthreads();
    }
}

__launch_bounds__(256)
__global__ void k_scatter(const int* __restrict__ ei, int E,
                          const int* __restrict__ rowstart,
                          int* __restrict__ fill, int* __restrict__ csr)
{
    int e = blockIdx.x * 256 + threadIdx.x;
    if (e >= E) return;
    int s = ei[e], d = ei[E + e];
    int pos = rowstart[d] + atomicAdd(&fill[d], 1);
    csr[pos] = s;
}

// ---------------------------------------------------------------------------
// GAT aggregation, HEADS=4, two-pass softmax, depth-8 prefetch / unroll-4.
// One wave per dst covers all heads; lane l: head=l>>4, dims (l&15)*8..+8.
// ---------------------------------------------------------------------------
__launch_bounds__(256)
__global__ void k_gat_agg_h4(const u16* __restrict__ hp,
                             const float* __restrict__ as_, const float* __restrict__ ad_,
                             const int* __restrict__ rowstart, const int* __restrict__ csr,
                             const float* __restrict__ bias, u16* __restrict__ out, int Nn)
{
    int d = (int)((blockIdx.x * (size_t)blockDim.x + threadIdx.x) >> 6);
    int lane = threadIdx.x & 63;
    if (d >= Nn) return;
    const int h = lane >> 4;
    const int li = lane & 15;
    const int dim = li * 8;
    int e0 = rowstart[d], e1 = rowstart[d + 1];
    float adv = ad_[(size_t)d * 4 + h];

    // ---- pass 1: per-head max (16 lanes per head stride the edge list) ----
    float mx = -INF_F;
    for (int j = e0 + li; j < e1; j += 16) {
        int s = csr[j];
        float e = as_[(size_t)s * 4 + h] + adv;
        e = e >= 0.f ? e : 0.2f * e;
        mx = fmaxf(mx, e);
    }
    #pragma unroll
    for (int m = 1; m < 16; m <<= 1) mx = fmaxf(mx, __shfl_xor(mx, m, 64));

    // ---- pass 2: depth-8 prefetch, unroll-4, no rescale ----
    float lsum = 0.f;
    float acc[8] = {};

    #define F4(J, A, U) { int jj = min((J), e1 - 1); int s_ = csr[jj];                \
        A = as_[(size_t)s_ * 4 + h];                                                  \
        U = *reinterpret_cast<const uint4*>(hp + ((size_t)s_ * 4 + h) * 128 + dim); }
    #define C4(A, U) { float e_ = A + adv; e_ = e_ >= 0.f ? e_ : 0.2f * e_;           \
        float w_ = __expf(e_ - mx); lsum += w_;                                       \
        float x_[8];                                                                  \
        bf2x(U.x, x_[0], x_[1]); bf2x(U.y, x_[2], x_[3]);                             \
        bf2x(U.z, x_[4], x_[5]); bf2x(U.w, x_[6], x_[7]);                             \
        _Pragma("unroll")                                                             \
        for (int t_ = 0; t_ < 8; ++t_) acc[t_] = fmaf(x_[t_], w_, acc[t_]); }

    float a0, a1, a2, a3, a4, a5, a6, a7;
    uint4 u0, u1, u2, u3, u4, u5, u6, u7;
    F4(e0 + 0, a0, u0); F4(e0 + 1, a1, u1); F4(e0 + 2, a2, u2); F4(e0 + 3, a3, u3);
    F4(e0 + 4, a4, u4); F4(e0 + 5, a5, u5); F4(e0 + 6, a6, u6); F4(e0 + 7, a7, u7);

    int j = e0;
    for (; j + 3 < e1; j += 4) {
        C4(a0, u0); C4(a1, u1); C4(a2, u2); C4(a3, u3);
        a0 = a4; u0 = u4; a1 = a5; u1 = u5; a2 = a6; u2 = u6; a3 = a7; u3 = u7;
        F4(j + 8, a4, u4); F4(j + 9, a5, u5); F4(j + 10, a6, u6); F4(j + 11, a7, u7);
    }
    if (j < e1)     C4(a0, u0);
    if (j + 1 < e1) C4(a1, u1);
    if (j + 2 < e1) C4(a2, u2);
    #undef F4
    #undef C4

    float inv = 1.f / (lsum + 1e-16f);
    const int ob = h * 128 + dim;
    float v[8];
    #pragma unroll
    for (int t = 0; t < 8; ++t) {
        float z = acc[t] * inv + bias[ob + t];
        v[t] = z >= 0.f ? z : 0.01f * z;
    }
    uint4 o;
    o.x = packbf(v[0], v[1]); o.y = packbf(v[2], v[3]);
    o.z = packbf(v[4], v[5]); o.w = packbf(v[6], v[7]);
    *reinterpret_cast<uint4*>(out + (size_t)d * 512 + ob) = o;
}

// ---------------------------------------------------------------------------
// GAT aggregation, HEADS=1, two-pass softmax, depth-8 prefetch / unroll-4.
// ---------------------------------------------------------------------------
__launch_bounds__(256)
__global__ void k_gat_agg_h1(const u16* __restrict__ hp,
                             const float* __restrict__ as_, const float* __restrict__ ad_,
                             const int* __restrict__ rowstart, const int* __restrict__ csr,
                             const float* __restrict__ bias, u16* __restrict__ out, int Nn)
{
    int d = (int)((blockIdx.x * (size_t)blockDim.x + threadIdx.x) >> 6);
    int lane = threadIdx.x & 63;
    if (d >= Nn) return;
    const int dim = lane * 2;
    int e0 = rowstart[d], e1 = rowstart[d + 1];
    float adv = ad_[d];

    // ---- pass 1: max, all 64 lanes stride edges ----
    float mx = -INF_F;
    for (int j = e0 + lane; j < e1; j += 64) {
        int s = csr[j];
        float e = as_[s] + adv;
        e = e >= 0.f ? e : 0.2f * e;
        mx = fmaxf(mx, e);
    }
    #pragma unroll
    for (int m = 1; m < 64; m <<= 1) mx = fmaxf(mx, __shfl_xor(mx, m, 64));

    // ---- pass 2: depth-8 prefetch, unroll-4 ----
    float lsum = 0.f, acc0 = 0.f, acc1 = 0.f;

    #define F1(J, A, U) { int jj = min((J), e1 - 1); int s_ = csr[jj];                \
        A = as_[s_];                                                                  \
        U = *reinterpret_cast<const unsigned int*>(hp + (size_t)s_ * 128 + dim); }
    #define C1(A, U) { float e_ = A + adv; e_ = e_ >= 0.f ? e_ : 0.2f * e_;           \
        float w_ = __expf(e_ - mx); float x0_, x1_; bf2x(U, x0_, x1_);                \
        lsum += w_; acc0 = fmaf(x0_, w_, acc0); acc1 = fmaf(x1_, w_, acc1); }

    float a0, a1, a2, a3, a4, a5, a6, a7;
    unsigned int u0, u1, u2, u3, u4, u5, u6, u7;
    F1(e0 + 0, a0, u0); F1(e0 + 1, a1, u1); F1(e0 + 2, a2, u2); F1(e0 + 3, a3, u3);
    F1(e0 + 4, a4, u4); F1(e0 + 5, a5, u5); F1(e0 + 6, a6, u6); F1(e0 + 7, a7, u7);

    int j = e0;
    for (; j + 3 < e1; j += 4) {
        C1(a0, u0); C1(a1, u1); C1(a2, u2); C1(a3, u3);
        a0 = a4; u0 = u4; a1 = a5; u1 = u5; a2 = a6; u2 = u6; a3 = a7; u3 = u7;
        F1(j + 8, a4, u4); F1(j + 9, a5, u5); F1(j + 10, a6, u6); F1(j + 11, a7, u7);
    }
    if (j < e1)     C1(a0, u0);
    if (j + 1 < e1) C1(a1, u1);
    if (j + 2 < e1) C1(a2, u2);
    #undef F1
    #undef C1

    float inv = 1.f / (lsum + 1e-16f);
    float v0 = acc0 * inv + bias[dim];
    float v1 = acc1 * inv + bias[dim + 1];
    v0 = v0 >= 0.f ? v0 : 0.01f * v0;
    v1 = v1 >= 0.f ? v1 : 0.01f * v1;
    *reinterpret_cast<unsigned int*>(out + (size_t)d * 128 + dim) = packbf(v0, v1);
}

// ---------------------------------------------------------------------------
extern "C" void kernel_launch(void* const* d_in, const int* in_sizes, int n_in,
                              void* d_out, int out_size, void* d_ws, size_t ws_size,
                              hipStream_t stream)
{
    const float* x     = (const float*)d_in[0];
    const int*   ei    = (const int*)  d_in[1];
    const float* fw_W  = (const float*)d_in[2];
    const float* fw_b  = (const float*)d_in[3];
    const float* c1_W  = (const float*)d_in[4];
    const float* c1_as = (const float*)d_in[5];
    const float* c1_ad = (const float*)d_in[6];
    const float* c1_b  = (const float*)d_in[7];
    const float* c2_W  = (const float*)d_in[8];
    const float* c2_as = (const float*)d_in[9];
    const float* c2_ad = (const float*)d_in[10];
    const float* c2_b  = (const float*)d_in[11];
    const float* bn1_g = (const float*)d_in[12];
    const float* bn1_b = (const float*)d_in[13];
    const float* bn2_g = (const float*)d_in[14];
    const float* bn2_b = (const float*)d_in[15];
    const float* bn3_g = (const float*)d_in[16];
    const float* bn3_b = (const float*)d_in[17];
    const float* l2_W  = (const float*)d_in[18];
    const float* l2_b  = (const float*)d_in[19];
    float* out = (float*)d_out;

    const int N = in_sizes[0] / 256;   // 50000
    const int E = in_sizes[1] / 2;     // 850000
    const int NB = 256;

    char* base = (char*)d_ws;
    size_t off = 0;
    auto alloc = [&](size_t bytes) -> void* {
        void* p = (void*)(base + off);
        off = (off + bytes + 255) & ~(size_t)255;
        return p;
    };
    // --- zeroed region (counts, fill) ---
    int*   counts = (int*)  alloc((size_t)N * 4);
    int*   fill   = (int*)  alloc((size_t)N * 4);
    size_t zero_bytes = off;
    // --- rest ---
    float* as1      = (float*)alloc((size_t)N * 4 * 4);
    float* ad1      = (float*)alloc((size_t)N * 4 * 4);
    float* as2      = (float*)alloc((size_t)N * 4);
    float* ad2      = (float*)alloc((size_t)N * 4);
    float* psum     = (float*)alloc((size_t)NB * 512 * 4);
    float* psq      = (float*)alloc((size_t)NB * 512 * 4);
    int*   rowstart = (int*)  alloc((size_t)(N + 1) * 4);
    int*   csr      = (int*)  alloc((size_t)E * 4);
    float* scale768 = (float*)alloc(768 * 4);
    float* shift768 = (float*)alloc(768 * 4);
    u16*   pb_l1    = (u16*)  alloc((size_t)256 * 128 * 2);
    u16*   pb_c1    = (u16*)  alloc((size_t)128 * 512 * 2);
    u16*   pb_c2    = (u16*)  alloc((size_t)512 * 128 * 2);
    u16*   pb_f     = (u16*)  alloc((size_t)768 * 64 * 2);
    u16*   h1       = (u16*)  alloc((size_t)N * 128 * 2);
    u16*   h2       = (u16*)  alloc((size_t)N * 512 * 2);
    u16*   hp1      = (u16*)  alloc((size_t)N * 512 * 2);  // dead after agg1:
    u16*   hp2      = hp1;                                  //  reuse for hp2 [N,128]
    u16*   h3       = hp1 + (size_t)N * 128;                //  and h3 [N,128]
    (void)ws_size; (void)n_in; (void)out_size;

    const int mb = (N + 63) / 64;
    const int wave_blocks = (int)(((size_t)N * 64 + 255) / 256);
    const int PK = 32768 + 65536 + 65536 + 49152;   // packed weight elements

    hipMemsetAsync(base, 0, zero_bytes, stream);

    // pack all weights + edge count (one launch)
    k_prep<<<(PK + E + 255) / 256, 256, 0, stream>>>(
        fw_W, c1_W, c2_W, l2_W, pb_l1, pb_c1, pb_c2, pb_f, ei + E, E, counts);

    k_scan<<<1, 1024, 0, stream>>>(counts, rowstart, N);
    k_scatter<<<(E + 255) / 256, 256, 0, stream>>>(ei, E, rowstart, fill, csr);

    // layer 1: h1 = lrelu(x @ fw_W + fw_b)
    k_mgemm<8, true, false, true, true, 0><<<dim3(1, mb), 256, 0, stream>>>(
        x, 256, 256, pb_l1, h1, 128, N, nullptr, nullptr, fw_b,
        nullptr, nullptr, nullptr, nullptr, 0);

    // BN1
    k_colstats<<<NB, 256, 0, stream>>>(h1, N, 128, psum, psq);
    k_colred<<<(128 + 3) / 4, 256, 0, stream>>>(psum, psq, bn1_g, bn1_b, NB, N, 128,
                                                scale768, shift768);

    // conv1 projection + fused alpha
    k_mgemm<16, false, true, false, false, 2><<<dim3(2, mb), 256, 0, stream>>>(
        h1, 128, 128, pb_c1, hp1, 512, N, scale768, shift768, nullptr,
        c1_as, c1_ad, as1, ad1, 4);
    k_gat_agg_h4<<<wave_blocks, 256, 0, stream>>>(
        hp1, as1, ad1, rowstart, csr, c1_b, h2, N);

    // BN2
    k_colstats<<<NB, 256, 0, stream>>>(h2, N, 512, psum, psq);
    k_colred<<<(512 + 3) / 4, 256, 0, stream>>>(psum, psq, bn2_g, bn2_b, NB, N, 512,
                                                scale768 + 128, shift768 + 128);

    // conv2 projection + fused alpha
    k_mgemm<8, false, true, false, false, 1><<<dim3(1, mb), 256, 0, stream>>>(
        h2, 512, 512, pb_c2, hp2, 128, N, scale768 + 128, shift768 + 128, nullptr,
        c2_as, c2_ad, as2, ad2, 1);
    k_gat_agg_h1<<<wave_blocks, 256, 0, stream>>>(
        hp2, as2, ad2, rowstart, csr, c2_b, h3, N);

    // BN3
    k_colstats<<<NB, 256, 0, stream>>>(h3, N, 128, psum, psq);
    k_colred<<<(128 + 3) / 4, 256, 0, stream>>>(psum, psq, bn3_g, bn3_b, NB, N, 128,
                                                scale768 + 640, shift768 + 640);

    // final fused GEMM + log_softmax
    k_mfinal<<<mb, 256, 0, stream>>>(h1, h2, h3, scale768, shift768, pb_f, l2_b, out, N);
}